// Round 1
// baseline (700.980 us; speedup 1.0000x reference)
//
#include <hip/hip_runtime.h>

// Problem constants (from reference): B=16, CIN=128, COUT=3, WDIM=512, H=W=256
#define B_    16
#define CIN_  128
#define COUT_ 3
#define WDIM_ 512
#define HW_   65536   // 256*256

// ---------------------------------------------------------------------------
// Kernel 1: coeff[b][i] = (w[b,:]·affine_w[i,:] + affine_b[i]) * weight[o,i]
// for o=0..2, packed as float4 (w component unused). 16 blocks x 128 threads.
// ---------------------------------------------------------------------------
__global__ __launch_bounds__(128) void style_coeff_kernel(
    const float* __restrict__ w,         // (B, WDIM)
    const float* __restrict__ weight,    // (COUT, CIN)
    const float* __restrict__ affine_w,  // (CIN, WDIM)
    const float* __restrict__ affine_b,  // (CIN,)
    float4* __restrict__ coeff)          // (B, CIN) float4
{
    const int b = blockIdx.x;
    const int c = threadIdx.x;  // channel 0..127

    const float4* wb = (const float4*)(w + (size_t)b * WDIM_);
    const float4* aw = (const float4*)(affine_w + (size_t)c * WDIM_);

    float s = 0.0f;
#pragma unroll 8
    for (int d = 0; d < WDIM_ / 4; ++d) {
        float4 a = aw[d];
        float4 v = wb[d];
        s += a.x * v.x + a.y * v.y + a.z * v.z + a.w * v.w;
    }
    s += affine_b[c];

    float4 o;
    o.x = s * weight[0 * CIN_ + c];
    o.y = s * weight[1 * CIN_ + c];
    o.z = s * weight[2 * CIN_ + c];
    o.w = 0.0f;
    coeff[(size_t)b * CIN_ + c] = o;
}

// ---------------------------------------------------------------------------
// Kernel 2: out[b,o,p] = sum_i x[b,i,p] * coeff[b][i][o] + bias[o]
// grid = (HW/1024, B), block = 256 threads, 4 pixels (float4) per thread.
// coeff staged in LDS (wave-uniform broadcast reads).
// ---------------------------------------------------------------------------
__global__ __launch_bounds__(256) void torgb_kernel(
    const float*  __restrict__ x,      // (B, CIN, HW)
    const float4* __restrict__ coeff,  // (B, CIN)
    const float*  __restrict__ bias,   // (COUT,)
    float*        __restrict__ out)    // (B, COUT, HW)
{
    __shared__ float4 sc[CIN_];

    const int b = blockIdx.y;
    const int t = threadIdx.x;

    if (t < CIN_) sc[t] = coeff[(size_t)b * CIN_ + t];
    __syncthreads();

    // float offset of this thread's 4-pixel group within a channel plane
    const size_t p4 = ((size_t)blockIdx.x * 256 + t) * 4;
    const float* xb = x + (size_t)b * CIN_ * HW_ + p4;

    float4 a0 = {0.f, 0.f, 0.f, 0.f};  // output channel 0, 4 pixels
    float4 a1 = {0.f, 0.f, 0.f, 0.f};  // output channel 1
    float4 a2 = {0.f, 0.f, 0.f, 0.f};  // output channel 2

#pragma unroll 8
    for (int i = 0; i < CIN_; ++i) {
        float4 xv = *(const float4*)(xb + (size_t)i * HW_);
        float4 c  = sc[i];
        a0.x = fmaf(xv.x, c.x, a0.x);
        a0.y = fmaf(xv.y, c.x, a0.y);
        a0.z = fmaf(xv.z, c.x, a0.z);
        a0.w = fmaf(xv.w, c.x, a0.w);
        a1.x = fmaf(xv.x, c.y, a1.x);
        a1.y = fmaf(xv.y, c.y, a1.y);
        a1.z = fmaf(xv.z, c.y, a1.z);
        a1.w = fmaf(xv.w, c.y, a1.w);
        a2.x = fmaf(xv.x, c.z, a2.x);
        a2.y = fmaf(xv.y, c.z, a2.y);
        a2.z = fmaf(xv.z, c.z, a2.z);
        a2.w = fmaf(xv.w, c.z, a2.w);
    }

    const float b0 = bias[0], b1 = bias[1], b2 = bias[2];
    float* ob = out + (size_t)b * COUT_ * HW_ + p4;

    float4 r0 = {a0.x + b0, a0.y + b0, a0.z + b0, a0.w + b0};
    float4 r1 = {a1.x + b1, a1.y + b1, a1.z + b1, a1.w + b1};
    float4 r2 = {a2.x + b2, a2.y + b2, a2.z + b2, a2.w + b2};

    *(float4*)(ob + 0 * (size_t)HW_) = r0;
    *(float4*)(ob + 1 * (size_t)HW_) = r1;
    *(float4*)(ob + 2 * (size_t)HW_) = r2;
}

extern "C" void kernel_launch(void* const* d_in, const int* in_sizes, int n_in,
                              void* d_out, int out_size, void* d_ws, size_t ws_size,
                              hipStream_t stream) {
    const float* x        = (const float*)d_in[0];  // (16,128,256,256)
    const float* w        = (const float*)d_in[1];  // (16,512)
    const float* weight   = (const float*)d_in[2];  // (3,128,1,1)
    const float* bias     = (const float*)d_in[3];  // (3,)
    const float* affine_w = (const float*)d_in[4];  // (128,512)
    const float* affine_b = (const float*)d_in[5];  // (128,)
    float* out = (float*)d_out;                     // (16,3,256,256)

    float4* coeff = (float4*)d_ws;                  // 16*128*16 B = 32 KB

    style_coeff_kernel<<<dim3(B_), dim3(CIN_), 0, stream>>>(
        w, weight, affine_w, affine_b, coeff);

    dim3 grid(HW_ / (4 * 256), B_);  // (64, 16) = 1024 blocks
    torgb_kernel<<<grid, dim3(256), 0, stream>>>(x, coeff, bias, out);
}

// Round 3
// 675.109 us; speedup vs baseline: 1.0383x; 1.0383x over previous
//
#include <hip/hip_runtime.h>

// Problem constants (from reference): B=16, CIN=128, COUT=3, WDIM=512, H=W=256
#define B_    16
#define CIN_  128
#define COUT_ 3
#define WDIM_ 512
#define HW_   65536   // 256*256

// Native vector type for nontemporal builtins (HIP float4 is a class and is
// rejected by __builtin_nontemporal_load/store; ext_vector_type works).
typedef float fvec4 __attribute__((ext_vector_type(4)));

// ---------------------------------------------------------------------------
// Kernel 1: coeff[b][i] = (w[b,:]·affine_w[i,:] + affine_b[i]) * weight[o,i]
// for o=0..2, packed as fvec4 (w component unused). 16 blocks x 128 threads.
// ---------------------------------------------------------------------------
__global__ __launch_bounds__(128) void style_coeff_kernel(
    const float* __restrict__ w,         // (B, WDIM)
    const float* __restrict__ weight,    // (COUT, CIN)
    const float* __restrict__ affine_w,  // (CIN, WDIM)
    const float* __restrict__ affine_b,  // (CIN,)
    fvec4* __restrict__ coeff)           // (B, CIN) fvec4
{
    const int b = blockIdx.x;
    const int c = threadIdx.x;  // channel 0..127

    const fvec4* wb = (const fvec4*)(w + (size_t)b * WDIM_);
    const fvec4* aw = (const fvec4*)(affine_w + (size_t)c * WDIM_);

    float s = 0.0f;
#pragma unroll 8
    for (int d = 0; d < WDIM_ / 4; ++d) {
        fvec4 a = aw[d];
        fvec4 v = wb[d];
        s += a.x * v.x + a.y * v.y + a.z * v.z + a.w * v.w;
    }
    s += affine_b[c];

    fvec4 o;
    o.x = s * weight[0 * CIN_ + c];
    o.y = s * weight[1 * CIN_ + c];
    o.z = s * weight[2 * CIN_ + c];
    o.w = 0.0f;
    coeff[(size_t)b * CIN_ + c] = o;
}

// ---------------------------------------------------------------------------
// Kernel 2: out[b,o,p] = sum_i x[b,i,p] * coeff[b][i][o] + bias[o]
// grid = (HW/1024, B), block = 256 threads, 4 pixels (fvec4) per thread.
// coeff staged in LDS (wave-uniform broadcast reads, conflict-free).
// x is a 512 MiB single-touch stream -> nontemporal loads (nt: skip L2/L3
// pollution). out likewise single-touch -> nontemporal stores.
// ---------------------------------------------------------------------------
__global__ __launch_bounds__(256) void torgb_kernel(
    const float*  __restrict__ x,      // (B, CIN, HW)
    const fvec4*  __restrict__ coeff,  // (B, CIN)
    const float*  __restrict__ bias,   // (COUT,)
    float*        __restrict__ out)    // (B, COUT, HW)
{
    __shared__ fvec4 sc[CIN_];

    const int b = blockIdx.y;
    const int t = threadIdx.x;

    if (t < CIN_) sc[t] = coeff[(size_t)b * CIN_ + t];
    __syncthreads();

    // float offset of this thread's 4-pixel group within a channel plane
    const size_t p4 = ((size_t)blockIdx.x * 256 + t) * 4;
    const float* xb = x + (size_t)b * CIN_ * HW_ + p4;

    fvec4 a0 = {0.f, 0.f, 0.f, 0.f};  // output channel 0, 4 pixels
    fvec4 a1 = {0.f, 0.f, 0.f, 0.f};  // output channel 1
    fvec4 a2 = {0.f, 0.f, 0.f, 0.f};  // output channel 2

#pragma unroll 16
    for (int i = 0; i < CIN_; ++i) {
        fvec4 xv = __builtin_nontemporal_load((const fvec4*)(xb + (size_t)i * HW_));
        fvec4 c  = sc[i];
        a0.x = fmaf(xv.x, c.x, a0.x);
        a0.y = fmaf(xv.y, c.x, a0.y);
        a0.z = fmaf(xv.z, c.x, a0.z);
        a0.w = fmaf(xv.w, c.x, a0.w);
        a1.x = fmaf(xv.x, c.y, a1.x);
        a1.y = fmaf(xv.y, c.y, a1.y);
        a1.z = fmaf(xv.z, c.y, a1.z);
        a1.w = fmaf(xv.w, c.y, a1.w);
        a2.x = fmaf(xv.x, c.z, a2.x);
        a2.y = fmaf(xv.y, c.z, a2.y);
        a2.z = fmaf(xv.z, c.z, a2.z);
        a2.w = fmaf(xv.w, c.z, a2.w);
    }

    const float b0 = bias[0], b1 = bias[1], b2 = bias[2];
    float* ob = out + (size_t)b * COUT_ * HW_ + p4;

    fvec4 r0 = {a0.x + b0, a0.y + b0, a0.z + b0, a0.w + b0};
    fvec4 r1 = {a1.x + b1, a1.y + b1, a1.z + b1, a1.w + b1};
    fvec4 r2 = {a2.x + b2, a2.y + b2, a2.z + b2, a2.w + b2};

    __builtin_nontemporal_store(r0, (fvec4*)(ob + 0 * (size_t)HW_));
    __builtin_nontemporal_store(r1, (fvec4*)(ob + 1 * (size_t)HW_));
    __builtin_nontemporal_store(r2, (fvec4*)(ob + 2 * (size_t)HW_));
}

extern "C" void kernel_launch(void* const* d_in, const int* in_sizes, int n_in,
                              void* d_out, int out_size, void* d_ws, size_t ws_size,
                              hipStream_t stream) {
    const float* x        = (const float*)d_in[0];  // (16,128,256,256)
    const float* w        = (const float*)d_in[1];  // (16,512)
    const float* weight   = (const float*)d_in[2];  // (3,128,1,1)
    const float* bias     = (const float*)d_in[3];  // (3,)
    const float* affine_w = (const float*)d_in[4];  // (128,512)
    const float* affine_b = (const float*)d_in[5];  // (128,)
    float* out = (float*)d_out;                     // (16,3,256,256)

    fvec4* coeff = (fvec4*)d_ws;                    // 16*128*16 B = 32 KB

    style_coeff_kernel<<<dim3(B_), dim3(CIN_), 0, stream>>>(
        w, weight, affine_w, affine_b, coeff);

    dim3 grid(HW_ / (4 * 256), B_);  // (64, 16) = 1024 blocks
    torgb_kernel<<<grid, dim3(256), 0, stream>>>(x, coeff, bias, out);
}